// Round 1
// baseline (904.970 us; speedup 1.0000x reference)
//
#include <hip/hip_runtime.h>

// Problem constants (from reference)
constexpr int NN = 50000;   // nodes
constexpr int NE = 800000;  // edges
constexpr int CI = 16;      // in channels
constexpr int CO = 64;      // out channels
constexpr int DD = 7;       // decoder dim

// ============================= CSR build =============================

__global__ void k_edge_deg_count(const int* __restrict__ src, const int* __restrict__ dst,
                                 const float* __restrict__ ew,
                                 float* __restrict__ deg, int* __restrict__ count) {
    int e = blockIdx.x * 256 + threadIdx.x;
    if (e >= NE) return;
    int s = src[e], d = dst[e];
    float w = (s == d) ? 0.f : ew[e];
    atomicAdd(&deg[s], w);
    atomicAdd(&count[d], 1);
}

__global__ void k_dinv(float* __restrict__ deg) {
    int i = blockIdx.x * 256 + threadIdx.x;
    if (i < NN) { float d = deg[i]; deg[i] = (d > 0.f) ? (1.f / sqrtf(d)) : 0.f; }
}

// inclusive scan of `count` in 1024-element chunks
__global__ void k_scan1(const int* __restrict__ count, int* __restrict__ S, int* __restrict__ bsums) {
    __shared__ int ts[256];
    int tid = threadIdx.x;
    int base = blockIdx.x * 1024;
    int vals[4]; int s = 0;
#pragma unroll
    for (int j = 0; j < 4; j++) {
        int idx = base + tid * 4 + j;
        int v = (idx < NN) ? count[idx] : 0;
        s += v; vals[j] = s;
    }
    ts[tid] = s;
    __syncthreads();
    for (int off = 1; off < 256; off <<= 1) {
        int v = (tid >= off) ? ts[tid - off] : 0;
        __syncthreads();
        ts[tid] += v;
        __syncthreads();
    }
    int prev = (tid > 0) ? ts[tid - 1] : 0;
#pragma unroll
    for (int j = 0; j < 4; j++) {
        int idx = base + tid * 4 + j;
        if (idx < NN) S[idx] = vals[j] + prev;
    }
    if (tid == 255) bsums[blockIdx.x] = ts[255];
}

__global__ void k_scan2(int* __restrict__ bsums, int nb) {
    if (threadIdx.x == 0 && blockIdx.x == 0) {
        int run = 0;
        for (int i = 0; i < nb; i++) { int v = bsums[i]; bsums[i] = run; run += v; }
    }
}

__global__ void k_scan3(const int* __restrict__ S, const int* __restrict__ count,
                        const int* __restrict__ bsums,
                        int* __restrict__ fill, int* __restrict__ rowptr) {
    int i = blockIdx.x * 256 + threadIdx.x;
    if (i >= NN) return;
    int tot = S[i] + bsums[i >> 10];
    rowptr[i + 1] = tot;
    fill[i] = tot - count[i];
    if (i == 0) rowptr[0] = 0;
}

__global__ void k_scatter(const int* __restrict__ src, const int* __restrict__ dst,
                          const float* __restrict__ ew, const float* __restrict__ dinv,
                          int* __restrict__ fill, int* __restrict__ csr_src,
                          float* __restrict__ csr_w) {
    int e = blockIdx.x * 256 + threadIdx.x;
    if (e >= NE) return;
    int s = src[e], d = dst[e];
    float w = (s == d) ? 0.f : ew[e];
    float nw = -dinv[s] * w * dinv[d];
    int pos = atomicAdd(&fill[d], 1);
    csr_src[pos] = s;
    csr_w[pos] = nw;
}

// ============================= propagation =============================
// out[n][:] = scale * sum_{e in row n} w_e * v[src_e][:]  (- sub[n][:] if sub)

// C=64: wave per node; lane = 16*j + cg; j = edge sub-slot (4 edges in flight),
// cg = float4 channel group. 256B coalesced gather per edge.
__global__ void __launch_bounds__(256) k_prop64(
    const float4* __restrict__ v, const float4* __restrict__ sub, float scale,
    const int* __restrict__ rowptr, const int* __restrict__ csr_src,
    const float* __restrict__ csr_w, float4* __restrict__ out) {
    int n = (blockIdx.x * 256 + threadIdx.x) >> 6;
    if (n >= NN) return;
    int lane = threadIdx.x & 63;
    int j = lane >> 4, cg = lane & 15;
    int beg = rowptr[n], end = rowptr[n + 1];
    float4 acc = make_float4(0.f, 0.f, 0.f, 0.f);
    for (int e = beg + j; e < end; e += 4) {
        int s = csr_src[e];
        float w = csr_w[e];
        float4 xv = v[s * 16 + cg];
        acc.x += w * xv.x; acc.y += w * xv.y; acc.z += w * xv.z; acc.w += w * xv.w;
    }
#pragma unroll
    for (int m = 16; m <= 32; m <<= 1) {
        acc.x += __shfl_xor(acc.x, m, 64);
        acc.y += __shfl_xor(acc.y, m, 64);
        acc.z += __shfl_xor(acc.z, m, 64);
        acc.w += __shfl_xor(acc.w, m, 64);
    }
    if (lane < 16) {
        float4 o;
        o.x = scale * acc.x; o.y = scale * acc.y; o.z = scale * acc.z; o.w = scale * acc.w;
        if (sub) {
            float4 sv = sub[n * 16 + cg];
            o.x -= sv.x; o.y -= sv.y; o.z -= sv.z; o.w -= sv.w;
        }
        out[n * 16 + cg] = o;
    }
}

// C=16: wave per node; 16 edges in flight, 4 float4-groups per row.
__global__ void __launch_bounds__(256) k_prop16(
    const float4* __restrict__ v, const float4* __restrict__ sub, float scale,
    const int* __restrict__ rowptr, const int* __restrict__ csr_src,
    const float* __restrict__ csr_w, float4* __restrict__ out) {
    int n = (blockIdx.x * 256 + threadIdx.x) >> 6;
    if (n >= NN) return;
    int lane = threadIdx.x & 63;
    int j = lane >> 2, cg = lane & 3;
    int beg = rowptr[n], end = rowptr[n + 1];
    float4 acc = make_float4(0.f, 0.f, 0.f, 0.f);
    for (int e = beg + j; e < end; e += 16) {
        int s = csr_src[e];
        float w = csr_w[e];
        float4 xv = v[s * 4 + cg];
        acc.x += w * xv.x; acc.y += w * xv.y; acc.z += w * xv.z; acc.w += w * xv.w;
    }
#pragma unroll
    for (int m = 4; m <= 32; m <<= 1) {
        acc.x += __shfl_xor(acc.x, m, 64);
        acc.y += __shfl_xor(acc.y, m, 64);
        acc.z += __shfl_xor(acc.z, m, 64);
        acc.w += __shfl_xor(acc.w, m, 64);
    }
    if (lane < 4) {
        float4 o;
        o.x = scale * acc.x; o.y = scale * acc.y; o.z = scale * acc.z; o.w = scale * acc.w;
        if (sub) {
            float4 sv = sub[n * 4 + cg];
            o.x -= sv.x; o.y -= sv.y; o.z -= sv.z; o.w -= sv.w;
        }
        out[n * 4 + cg] = o;
    }
}

// ============================= dense gates =============================

// Gx[n][g*64+co] = sum_k sum_ci xcat[n][k*16+ci] * Wx[g][k][ci][co] + bx[g][co]
__global__ void __launch_bounds__(256) k_gemm_x(
    const float* __restrict__ x, const float* __restrict__ Tx1, const float* __restrict__ Tx2,
    const float* __restrict__ Wx, const float* __restrict__ bx, float* __restrict__ Gx) {
    __shared__ float Wlds[48 * 192];
    __shared__ float blds[192];
    for (int i = threadIdx.x; i < 48 * 192; i += 256) {
        int co = i & 63, u = i >> 6, ci = u & 15, t = u >> 4, k = t % 3, g = t / 3;
        Wlds[(k * 16 + ci) * 192 + g * 64 + co] = Wx[i];
    }
    for (int i = threadIdx.x; i < 192; i += 256) blds[i] = bx[i];
    __syncthreads();
    int lane = threadIdx.x & 63;
    int wid = threadIdx.x >> 6;
    for (int n = blockIdx.x * 4 + wid; n < NN; n += gridDim.x * 4) {
        float vx = 0.f;
        if (lane < 16) vx = x[n * 16 + lane];
        else if (lane < 32) vx = Tx1[n * 16 + lane - 16];
        else if (lane < 48) vx = Tx2[n * 16 + lane - 32];
        float a0 = blds[lane], a1 = blds[64 + lane], a2 = blds[128 + lane];
#pragma unroll
        for (int ci = 0; ci < 48; ci++) {
            float v = __shfl(vx, ci, 64);
            a0 += v * Wlds[ci * 192 + lane];
            a1 += v * Wlds[ci * 192 + 64 + lane];
            a2 += v * Wlds[ci * 192 + 128 + lane];
        }
        Gx[n * 192 + lane] = a0;
        Gx[n * 192 + 64 + lane] = a1;
        Gx[n * 192 + 128 + lane] = a2;
    }
}

// h-side gate: P = Gx_col + bh[g] + [in0|in1|in2] @ Wh[g]
// mode 0: out = sigmoid(P)                 (z)
// mode 1: out = sigmoid(P) * h0            (hr)
// mode 2: out = z*h0 + (1-z)*tanh(P)       (h)
__global__ void __launch_bounds__(256) k_gemm_h(
    const float* __restrict__ in0, const float* __restrict__ in1, const float* __restrict__ in2,
    const float* __restrict__ Whg, const float* __restrict__ bhg,
    const float* __restrict__ GxCol, const float* __restrict__ h0,
    const float* __restrict__ zbuf, float* __restrict__ outbuf, int mode) {
    __shared__ float Wlds[192 * 64];
    for (int i = threadIdx.x; i < 192 * 64; i += 256) Wlds[i] = Whg[i];
    __syncthreads();
    int lane = threadIdx.x & 63;
    int wid = threadIdx.x >> 6;
    float b = bhg[lane];
    for (int n = blockIdx.x * 4 + wid; n < NN; n += gridDim.x * 4) {
        float v0 = in0[n * 64 + lane];
        float v1 = in1[n * 64 + lane];
        float v2 = in2[n * 64 + lane];
        float acc = b + GxCol[n * 192 + lane];
#pragma unroll
        for (int ci = 0; ci < 64; ci++) acc += __shfl(v0, ci, 64) * Wlds[ci * 64 + lane];
#pragma unroll
        for (int ci = 0; ci < 64; ci++) acc += __shfl(v1, ci, 64) * Wlds[(64 + ci) * 64 + lane];
#pragma unroll
        for (int ci = 0; ci < 64; ci++) acc += __shfl(v2, ci, 64) * Wlds[(128 + ci) * 64 + lane];
        if (mode == 0) {
            outbuf[n * 64 + lane] = 1.f / (1.f + __expf(-acc));
        } else if (mode == 1) {
            float r = 1.f / (1.f + __expf(-acc));
            outbuf[n * 64 + lane] = r * h0[n * 64 + lane];
        } else {
            float ht = tanhf(acc);
            float zv = zbuf[n * 64 + lane];
            float h0v = h0[n * 64 + lane];
            outbuf[n * 64 + lane] = zv * h0v + (1.f - zv) * ht;
        }
    }
}

// y = relu(h) @ Wlin + blin
__global__ void k_ylin(const float* __restrict__ h, const float* __restrict__ Wlin,
                       const float* __restrict__ blin, float* __restrict__ y) {
    int t = blockIdx.x * 256 + threadIdx.x;
    int n = t >> 3, d = t & 7;
    if (n >= NN || d >= DD) return;
    float acc = blin[d];
#pragma unroll 8
    for (int c = 0; c < 64; c++) acc += fmaxf(h[n * 64 + c], 0.f) * Wlin[c * DD + d];
    y[n * DD + d] = acc;
}

// ============================= launch =============================

extern "C" void kernel_launch(void* const* d_in, const int* in_sizes, int n_in,
                              void* d_out, int out_size, void* d_ws, size_t ws_size,
                              hipStream_t stream) {
    (void)in_sizes; (void)n_in; (void)out_size; (void)ws_size;
    const float* x    = (const float*)d_in[0];
    const int*   eidx = (const int*)d_in[1];
    const float* ew   = (const float*)d_in[2];
    const float* h0   = (const float*)d_in[3];
    const float* Wx   = (const float*)d_in[4];
    const float* Wh   = (const float*)d_in[5];
    const float* bx   = (const float*)d_in[6];
    const float* bh   = (const float*)d_in[7];
    const float* Wlin = (const float*)d_in[8];
    const float* blin = (const float*)d_in[9];
    const int* src = eidx;
    const int* dst = eidx + NE;

    char* ws = (char*)d_ws;
    size_t off = 0;
    auto alloc = [&](size_t nbytes) -> void* {
        void* p = ws + off;
        off += (nbytes + 255) & ~(size_t)255;
        return p;
    };
    float* dinv    = (float*)alloc(NN * 4);
    int*   count   = (int*)alloc(NN * 4);
    int*   S       = (int*)alloc(NN * 4);
    int*   fill    = (int*)alloc(NN * 4);
    int*   rowptr  = (int*)alloc((NN + 1) * 4);
    int*   bsums   = (int*)alloc(64 * 4);
    int*   csr_src = (int*)alloc(NE * 4);
    float* csr_w   = (float*)alloc(NE * 4);
    float* Tx1     = (float*)alloc((size_t)NN * CI * 4);
    float* Tx2     = (float*)alloc((size_t)NN * CI * 4);
    float* Th1     = (float*)alloc((size_t)NN * CO * 4);
    float* Th2     = (float*)alloc((size_t)NN * CO * 4);
    float* hr      = (float*)alloc((size_t)NN * CO * 4);
    float* z       = (float*)alloc((size_t)NN * CO * 4);
    float* Gx      = (float*)alloc((size_t)NN * 192 * 4);

    float* hout = (float*)d_out;
    float* yout = hout + (size_t)NN * CO;

    constexpr int NB = (NN + 1023) / 1024;  // scan chunks
    const int EB = (NE + 255) / 256;
    const int NBLK = (NN + 255) / 256;
    const int PROPB = (NN + 3) / 4;  // 4 waves/block, wave per node

    hipMemsetAsync(dinv, 0, NN * 4, stream);
    hipMemsetAsync(count, 0, NN * 4, stream);

    k_edge_deg_count<<<EB, 256, 0, stream>>>(src, dst, ew, dinv, count);
    k_dinv<<<NBLK, 256, 0, stream>>>(dinv);
    k_scan1<<<NB, 256, 0, stream>>>(count, S, bsums);
    k_scan2<<<1, 64, 0, stream>>>(bsums, NB);
    k_scan3<<<NBLK, 256, 0, stream>>>(S, count, bsums, fill, rowptr);
    k_scatter<<<EB, 256, 0, stream>>>(src, dst, ew, dinv, fill, csr_src, csr_w);

    // Chebyshev propagation for x (C=16): Tx1 = prop(x); Tx2 = 2*prop(Tx1) - x
    k_prop16<<<PROPB, 256, 0, stream>>>((const float4*)x, nullptr, 1.f, rowptr, csr_src, csr_w, (float4*)Tx1);
    k_prop16<<<PROPB, 256, 0, stream>>>((const float4*)Tx1, (const float4*)x, 2.f, rowptr, csr_src, csr_w, (float4*)Tx2);
    // Chebyshev propagation for h0 (C=64)
    k_prop64<<<PROPB, 256, 0, stream>>>((const float4*)h0, nullptr, 1.f, rowptr, csr_src, csr_w, (float4*)Th1);
    k_prop64<<<PROPB, 256, 0, stream>>>((const float4*)Th1, (const float4*)h0, 2.f, rowptr, csr_src, csr_w, (float4*)Th2);

    // x-side pre-activations for all 3 gates
    k_gemm_x<<<1024, 256, 0, stream>>>(x, Tx1, Tx2, Wx, bx, Gx);
    // z gate
    k_gemm_h<<<768, 256, 0, stream>>>(h0, Th1, Th2, Wh, bh, Gx, h0, nullptr, z, 0);
    // r gate -> hr = r * h0
    k_gemm_h<<<768, 256, 0, stream>>>(h0, Th1, Th2, Wh + 3 * 64 * 64, bh + 64, Gx + 64, h0, nullptr, hr, 1);
    // propagate hr (reuse Th1/Th2 as Thr1/Thr2)
    k_prop64<<<PROPB, 256, 0, stream>>>((const float4*)hr, nullptr, 1.f, rowptr, csr_src, csr_w, (float4*)Th1);
    k_prop64<<<PROPB, 256, 0, stream>>>((const float4*)Th1, (const float4*)hr, 2.f, rowptr, csr_src, csr_w, (float4*)Th2);
    // htilde gate -> h (written directly to d_out)
    k_gemm_h<<<768, 256, 0, stream>>>(hr, Th1, Th2, Wh + 6 * 64 * 64, bh + 128, Gx + 128, h0, z, hout, 2);
    // decoder
    k_ylin<<<(NN * 8 + 255) / 256, 256, 0, stream>>>(hout, Wlin, blin, yout);
}

// Round 2
// 461.799 us; speedup vs baseline: 1.9597x; 1.9597x over previous
//
#include <hip/hip_runtime.h>

// Problem constants (from reference)
constexpr int NN = 50000;   // nodes
constexpr int NE = 800000;  // edges
constexpr int CI = 16;      // in channels
constexpr int CO = 64;      // out channels
constexpr int DD = 7;       // decoder dim

typedef __bf16 bf16x8 __attribute__((ext_vector_type(8)));
typedef float  f32x4  __attribute__((ext_vector_type(4)));

// ============================= CSR build =============================

__global__ void k_edge_deg_count(const int* __restrict__ src, const int* __restrict__ dst,
                                 const float* __restrict__ ew,
                                 float* __restrict__ deg, int* __restrict__ count) {
    int e = blockIdx.x * 256 + threadIdx.x;
    if (e >= NE) return;
    int s = src[e], d = dst[e];
    float w = (s == d) ? 0.f : ew[e];
    atomicAdd(&deg[s], w);
    atomicAdd(&count[d], 1);
}

__global__ void k_dinv(float* __restrict__ deg) {
    int i = blockIdx.x * 256 + threadIdx.x;
    if (i < NN) { float d = deg[i]; deg[i] = (d > 0.f) ? (1.f / sqrtf(d)) : 0.f; }
}

// inclusive scan of `count` in 1024-element chunks
__global__ void k_scan1(const int* __restrict__ count, int* __restrict__ S, int* __restrict__ bsums) {
    __shared__ int ts[256];
    int tid = threadIdx.x;
    int base = blockIdx.x * 1024;
    int vals[4]; int s = 0;
#pragma unroll
    for (int j = 0; j < 4; j++) {
        int idx = base + tid * 4 + j;
        int v = (idx < NN) ? count[idx] : 0;
        s += v; vals[j] = s;
    }
    ts[tid] = s;
    __syncthreads();
    for (int off = 1; off < 256; off <<= 1) {
        int v = (tid >= off) ? ts[tid - off] : 0;
        __syncthreads();
        ts[tid] += v;
        __syncthreads();
    }
    int prev = (tid > 0) ? ts[tid - 1] : 0;
#pragma unroll
    for (int j = 0; j < 4; j++) {
        int idx = base + tid * 4 + j;
        if (idx < NN) S[idx] = vals[j] + prev;
    }
    if (tid == 255) bsums[blockIdx.x] = ts[255];
}

__global__ void k_scan2(int* __restrict__ bsums, int nb) {
    if (threadIdx.x == 0 && blockIdx.x == 0) {
        int run = 0;
        for (int i = 0; i < nb; i++) { int v = bsums[i]; bsums[i] = run; run += v; }
    }
}

__global__ void k_scan3(const int* __restrict__ S, const int* __restrict__ count,
                        const int* __restrict__ bsums,
                        int* __restrict__ fill, int* __restrict__ rowptr) {
    int i = blockIdx.x * 256 + threadIdx.x;
    if (i >= NN) return;
    int tot = S[i] + bsums[i >> 10];
    rowptr[i + 1] = tot;
    fill[i] = tot - count[i];
    if (i == 0) rowptr[0] = 0;
}

__global__ void k_scatter(const int* __restrict__ src, const int* __restrict__ dst,
                          const float* __restrict__ ew, const float* __restrict__ dinv,
                          int* __restrict__ fill, int* __restrict__ csr_src,
                          float* __restrict__ csr_w) {
    int e = blockIdx.x * 256 + threadIdx.x;
    if (e >= NE) return;
    int s = src[e], d = dst[e];
    float w = (s == d) ? 0.f : ew[e];
    float nw = -dinv[s] * w * dinv[d];
    int pos = atomicAdd(&fill[d], 1);
    csr_src[pos] = s;
    csr_w[pos] = nw;
}

// ============================= propagation =============================
// out[n][:] = scale * sum_{e in row n} w_e * v[src_e][:]  (- sub[n][:] if sub)

__global__ void __launch_bounds__(256) k_prop64(
    const float4* __restrict__ v, const float4* __restrict__ sub, float scale,
    const int* __restrict__ rowptr, const int* __restrict__ csr_src,
    const float* __restrict__ csr_w, float4* __restrict__ out) {
    int n = (blockIdx.x * 256 + threadIdx.x) >> 6;
    if (n >= NN) return;
    int lane = threadIdx.x & 63;
    int j = lane >> 4, cg = lane & 15;
    int beg = rowptr[n], end = rowptr[n + 1];
    float4 acc = make_float4(0.f, 0.f, 0.f, 0.f);
    for (int e = beg + j; e < end; e += 4) {
        int s = csr_src[e];
        float w = csr_w[e];
        float4 xv = v[s * 16 + cg];
        acc.x += w * xv.x; acc.y += w * xv.y; acc.z += w * xv.z; acc.w += w * xv.w;
    }
#pragma unroll
    for (int m = 16; m <= 32; m <<= 1) {
        acc.x += __shfl_xor(acc.x, m, 64);
        acc.y += __shfl_xor(acc.y, m, 64);
        acc.z += __shfl_xor(acc.z, m, 64);
        acc.w += __shfl_xor(acc.w, m, 64);
    }
    if (lane < 16) {
        float4 o;
        o.x = scale * acc.x; o.y = scale * acc.y; o.z = scale * acc.z; o.w = scale * acc.w;
        if (sub) {
            float4 sv = sub[n * 16 + cg];
            o.x -= sv.x; o.y -= sv.y; o.z -= sv.z; o.w -= sv.w;
        }
        out[n * 16 + cg] = o;
    }
}

__global__ void __launch_bounds__(256) k_prop16(
    const float4* __restrict__ v, const float4* __restrict__ sub, float scale,
    const int* __restrict__ rowptr, const int* __restrict__ csr_src,
    const float* __restrict__ csr_w, float4* __restrict__ out) {
    int n = (blockIdx.x * 256 + threadIdx.x) >> 6;
    if (n >= NN) return;
    int lane = threadIdx.x & 63;
    int j = lane >> 2, cg = lane & 3;
    int beg = rowptr[n], end = rowptr[n + 1];
    float4 acc = make_float4(0.f, 0.f, 0.f, 0.f);
    for (int e = beg + j; e < end; e += 16) {
        int s = csr_src[e];
        float w = csr_w[e];
        float4 xv = v[s * 4 + cg];
        acc.x += w * xv.x; acc.y += w * xv.y; acc.z += w * xv.z; acc.w += w * xv.w;
    }
#pragma unroll
    for (int m = 4; m <= 32; m <<= 1) {
        acc.x += __shfl_xor(acc.x, m, 64);
        acc.y += __shfl_xor(acc.y, m, 64);
        acc.z += __shfl_xor(acc.z, m, 64);
        acc.w += __shfl_xor(acc.w, m, 64);
    }
    if (lane < 4) {
        float4 o;
        o.x = scale * acc.x; o.y = scale * acc.y; o.z = scale * acc.z; o.w = scale * acc.w;
        if (sub) {
            float4 sv = sub[n * 4 + cg];
            o.x -= sv.x; o.y -= sv.y; o.z -= sv.z; o.w -= sv.w;
        }
        out[n * 4 + cg] = o;
    }
}

// ============================= MFMA dense gates =============================
// Logical A row (K=256): [x(16) | Tx1(16) | Tx2(16) | h(64) | Th1(64) | Th2(64) | pad(16)]
// Logical B (K=256 x cols): rows 0-47 from Wx[g], rows 48-239 from Wh[g], rows 240+ zero.
// zr kernel: cols 0-63 = gate z, cols 64-127 = gate r.  ht kernel: cols 0-63 = gate htilde.

// Pre-swizzle B into MFMA fragment order: Bfrag[(t*8+kk)*64 + lane] is the bf16x8
// for out-tile t, K-step kk, lane l:  B[kk*32+(l>>4)*8+j][t*16+(l&15)]
__global__ void k_prep_b(const float* __restrict__ Wx, const float* __restrict__ Wh,
                         const float* __restrict__ bx, const float* __restrict__ bh,
                         bf16x8* __restrict__ BfragZR, bf16x8* __restrict__ BfragHT,
                         float* __restrict__ biasC) {
    int tid = blockIdx.x * 256 + threadIdx.x;
    if (tid < 6144) {
        int e = tid, gate, n, kk, l;
        if (e < 4096) {
            int t = e >> 9, rem = e & 511;
            kk = rem >> 6; l = rem & 63;
            n = t * 16 + (l & 15);
            gate = n >> 6;
        } else {
            int e2 = e - 4096;
            int t = e2 >> 9, rem = e2 & 511;
            kk = rem >> 6; l = rem & 63;
            n = t * 16 + (l & 15);
            gate = 2;
        }
        int co = n & 63;
        int k0 = kk * 32 + (l >> 4) * 8;
        bf16x8 f;
#pragma unroll
        for (int j = 0; j < 8; j++) {
            int k = k0 + j;
            float w = 0.f;
            if (k < 48) w = Wx[((gate * 3 + (k >> 4)) * 16 + (k & 15)) * 64 + co];
            else if (k < 240) { int kh = k - 48; w = Wh[((gate * 3 + (kh >> 6)) * 64 + (kh & 63)) * 64 + co]; }
            f[j] = (__bf16)w;
        }
        if (e < 4096) BfragZR[e] = f; else BfragHT[e - 4096] = f;
    } else if (tid < 6144 + 192) {
        int i = tid - 6144;
        biasC[i] = bx[i] + bh[i];
    }
}

__device__ inline bf16x8 load_a_frag(int c, int m,
                                     const float* __restrict__ x, const float* __restrict__ Tx1,
                                     const float* __restrict__ Tx2, const float* __restrict__ h,
                                     const float* __restrict__ Th1, const float* __restrict__ Th2) {
    bf16x8 a;
    if (c >= 30) {
#pragma unroll
        for (int j = 0; j < 8; j++) a[j] = (__bf16)0.f;
        return a;
    }
    const float* base; int off;
    if (c < 6) {
        base = (c < 2) ? x : ((c < 4) ? Tx1 : Tx2);
        off = m * 16 + (c & 1) * 8;
    } else {
        int d = c - 6;
        base = (d < 8) ? h : ((d < 16) ? Th1 : Th2);
        off = m * 64 + (d & 7) * 8;
    }
    float4 u0 = *(const float4*)(base + off);
    float4 u1 = *(const float4*)(base + off + 4);
    a[0] = (__bf16)u0.x; a[1] = (__bf16)u0.y; a[2] = (__bf16)u0.z; a[3] = (__bf16)u0.w;
    a[4] = (__bf16)u1.x; a[5] = (__bf16)u1.y; a[6] = (__bf16)u1.z; a[7] = (__bf16)u1.w;
    return a;
}

// z and r gates: one wave per 16-node tile, 128 output cols (8 out-tiles).
__global__ void __launch_bounds__(256) k_mfma_zr(
    const float* __restrict__ x, const float* __restrict__ Tx1, const float* __restrict__ Tx2,
    const float* __restrict__ h0, const float* __restrict__ Th1, const float* __restrict__ Th2,
    const bf16x8* __restrict__ Bfrag, const float* __restrict__ biasC,
    float* __restrict__ z, float* __restrict__ hr) {
    int wv = (blockIdx.x * 256 + threadIdx.x) >> 6;
    if (wv >= NN / 16) return;
    int lane = threadIdx.x & 63;
    int q = lane >> 4, r16 = lane & 15;
    int ma = wv * 16 + r16;  // A row this lane loads
    f32x4 acc[8];
#pragma unroll
    for (int t = 0; t < 8; t++) acc[t] = (f32x4){0.f, 0.f, 0.f, 0.f};
#pragma unroll
    for (int kk = 0; kk < 8; kk++) {
        bf16x8 a = load_a_frag(kk * 4 + q, ma, x, Tx1, Tx2, h0, Th1, Th2);
#pragma unroll
        for (int t = 0; t < 8; t++)
            acc[t] = __builtin_amdgcn_mfma_f32_16x16x32_bf16(a, Bfrag[(t * 8 + kk) * 64 + lane], acc[t], 0, 0, 0);
    }
    int mbase = wv * 16 + q * 4;
#pragma unroll
    for (int t = 0; t < 8; t++) {
        int co = t * 16 + r16;      // 0..127
        float bias = biasC[co];
        int col = co & 63;
#pragma unroll
        for (int reg = 0; reg < 4; reg++) {
            int mm = mbase + reg;
            float p = acc[t][reg] + bias;
            float s = 1.f / (1.f + __expf(-p));
            if (t < 4) z[mm * 64 + col] = s;
            else       hr[mm * 64 + col] = s * h0[mm * 64 + col];
        }
    }
}

// htilde gate + GRU combine: one wave per 16-node tile, 64 output cols (4 out-tiles).
__global__ void __launch_bounds__(256) k_mfma_ht(
    const float* __restrict__ x, const float* __restrict__ Tx1, const float* __restrict__ Tx2,
    const float* __restrict__ hr, const float* __restrict__ Thr1, const float* __restrict__ Thr2,
    const bf16x8* __restrict__ Bfrag, const float* __restrict__ biasC,
    const float* __restrict__ z, const float* __restrict__ h0,
    float* __restrict__ hout) {
    int wv = (blockIdx.x * 256 + threadIdx.x) >> 6;
    if (wv >= NN / 16) return;
    int lane = threadIdx.x & 63;
    int q = lane >> 4, r16 = lane & 15;
    int ma = wv * 16 + r16;
    f32x4 acc[4];
#pragma unroll
    for (int t = 0; t < 4; t++) acc[t] = (f32x4){0.f, 0.f, 0.f, 0.f};
#pragma unroll
    for (int kk = 0; kk < 8; kk++) {
        bf16x8 a = load_a_frag(kk * 4 + q, ma, x, Tx1, Tx2, hr, Thr1, Thr2);
#pragma unroll
        for (int t = 0; t < 4; t++)
            acc[t] = __builtin_amdgcn_mfma_f32_16x16x32_bf16(a, Bfrag[(t * 8 + kk) * 64 + lane], acc[t], 0, 0, 0);
    }
    int mbase = wv * 16 + q * 4;
#pragma unroll
    for (int t = 0; t < 4; t++) {
        int co = t * 16 + r16;   // 0..63
        float bias = biasC[128 + co];
#pragma unroll
        for (int reg = 0; reg < 4; reg++) {
            int mm = mbase + reg;
            float p = acc[t][reg] + bias;
            float htl = tanhf(p);
            float zv = z[mm * 64 + co];
            float h0v = h0[mm * 64 + co];
            hout[mm * 64 + co] = zv * h0v + (1.f - zv) * htl;
        }
    }
}

// y = relu(h) @ Wlin + blin
__global__ void k_ylin(const float* __restrict__ h, const float* __restrict__ Wlin,
                       const float* __restrict__ blin, float* __restrict__ y) {
    int t = blockIdx.x * 256 + threadIdx.x;
    int n = t >> 3, d = t & 7;
    if (n >= NN || d >= DD) return;
    float acc = blin[d];
#pragma unroll 8
    for (int c = 0; c < 64; c++) acc += fmaxf(h[n * 64 + c], 0.f) * Wlin[c * DD + d];
    y[n * DD + d] = acc;
}

// ============================= launch =============================

extern "C" void kernel_launch(void* const* d_in, const int* in_sizes, int n_in,
                              void* d_out, int out_size, void* d_ws, size_t ws_size,
                              hipStream_t stream) {
    (void)in_sizes; (void)n_in; (void)out_size; (void)ws_size;
    const float* x    = (const float*)d_in[0];
    const int*   eidx = (const int*)d_in[1];
    const float* ew   = (const float*)d_in[2];
    const float* h0   = (const float*)d_in[3];
    const float* Wx   = (const float*)d_in[4];
    const float* Wh   = (const float*)d_in[5];
    const float* bx   = (const float*)d_in[6];
    const float* bh   = (const float*)d_in[7];
    const float* Wlin = (const float*)d_in[8];
    const float* blin = (const float*)d_in[9];
    const int* src = eidx;
    const int* dst = eidx + NE;

    char* ws = (char*)d_ws;
    size_t off = 0;
    auto alloc = [&](size_t nbytes) -> void* {
        void* p = ws + off;
        off += (nbytes + 255) & ~(size_t)255;
        return p;
    };
    float* dinv    = (float*)alloc(NN * 4);
    int*   count   = (int*)alloc(NN * 4);
    int*   S       = (int*)alloc(NN * 4);
    int*   fill    = (int*)alloc(NN * 4);
    int*   rowptr  = (int*)alloc((NN + 1) * 4);
    int*   bsums   = (int*)alloc(64 * 4);
    int*   csr_src = (int*)alloc(NE * 4);
    float* csr_w   = (float*)alloc(NE * 4);
    float* Tx1     = (float*)alloc((size_t)NN * CI * 4);
    float* Tx2     = (float*)alloc((size_t)NN * CI * 4);
    float* Th1     = (float*)alloc((size_t)NN * CO * 4);
    float* Th2     = (float*)alloc((size_t)NN * CO * 4);
    float* hr      = (float*)alloc((size_t)NN * CO * 4);
    float* z       = (float*)alloc((size_t)NN * CO * 4);
    bf16x8* BfragZR = (bf16x8*)alloc(4096 * 16);
    bf16x8* BfragHT = (bf16x8*)alloc(2048 * 16);
    float* biasC   = (float*)alloc(192 * 4);

    float* hout = (float*)d_out;
    float* yout = hout + (size_t)NN * CO;

    constexpr int NB = (NN + 1023) / 1024;  // scan chunks
    const int EB = (NE + 255) / 256;
    const int NBLK = (NN + 255) / 256;
    const int PROPB = (NN + 3) / 4;     // 4 waves/block, wave per node
    const int GEMMB = (NN / 16 * 64 + 255) / 256;  // wave per 16-node tile

    hipMemsetAsync(dinv, 0, NN * 4, stream);
    hipMemsetAsync(count, 0, NN * 4, stream);

    k_prep_b<<<25, 256, 0, stream>>>(Wx, Wh, bx, bh, BfragZR, BfragHT, biasC);
    k_edge_deg_count<<<EB, 256, 0, stream>>>(src, dst, ew, dinv, count);
    k_dinv<<<NBLK, 256, 0, stream>>>(dinv);
    k_scan1<<<NB, 256, 0, stream>>>(count, S, bsums);
    k_scan2<<<1, 64, 0, stream>>>(bsums, NB);
    k_scan3<<<NBLK, 256, 0, stream>>>(S, count, bsums, fill, rowptr);
    k_scatter<<<EB, 256, 0, stream>>>(src, dst, ew, dinv, fill, csr_src, csr_w);

    // Chebyshev propagation for x (C=16): Tx1 = prop(x); Tx2 = 2*prop(Tx1) - x
    k_prop16<<<PROPB, 256, 0, stream>>>((const float4*)x, nullptr, 1.f, rowptr, csr_src, csr_w, (float4*)Tx1);
    k_prop16<<<PROPB, 256, 0, stream>>>((const float4*)Tx1, (const float4*)x, 2.f, rowptr, csr_src, csr_w, (float4*)Tx2);
    // Chebyshev propagation for h0 (C=64)
    k_prop64<<<PROPB, 256, 0, stream>>>((const float4*)h0, nullptr, 1.f, rowptr, csr_src, csr_w, (float4*)Th1);
    k_prop64<<<PROPB, 256, 0, stream>>>((const float4*)Th1, (const float4*)h0, 2.f, rowptr, csr_src, csr_w, (float4*)Th2);

    // z and r gates (r fused into hr = r*h0)
    k_mfma_zr<<<GEMMB, 256, 0, stream>>>(x, Tx1, Tx2, h0, Th1, Th2, BfragZR, biasC, z, hr);
    // propagate hr (reuse Th1/Th2 as Thr1/Thr2)
    k_prop64<<<PROPB, 256, 0, stream>>>((const float4*)hr, nullptr, 1.f, rowptr, csr_src, csr_w, (float4*)Th1);
    k_prop64<<<PROPB, 256, 0, stream>>>((const float4*)Th1, (const float4*)hr, 2.f, rowptr, csr_src, csr_w, (float4*)Th2);
    // htilde gate + GRU combine -> h (written directly to d_out)
    k_mfma_ht<<<GEMMB, 256, 0, stream>>>(x, Tx1, Tx2, hr, Th1, Th2, BfragHT, biasC, z, h0, hout);
    // decoder
    k_ylin<<<(NN * 8 + 255) / 256, 256, 0, stream>>>(hout, Wlin, blin, yout);
}

// Round 3
// 391.927 us; speedup vs baseline: 2.3090x; 1.1783x over previous
//
#include <hip/hip_runtime.h>

// Problem constants (from reference)
constexpr int NN = 50000;   // nodes
constexpr int NE = 800000;  // edges
constexpr int CI = 16;      // in channels
constexpr int CO = 64;      // out channels
constexpr int DD = 7;       // decoder dim

typedef __bf16 bf16x8 __attribute__((ext_vector_type(8)));
typedef float  f32x4  __attribute__((ext_vector_type(4)));

__device__ inline float blo(unsigned u) { return __uint_as_float(u << 16); }
__device__ inline float bhi(unsigned u) { return __uint_as_float(u & 0xffff0000u); }

// ================= fused: edge histograms + bf16 casts + B-prep =================
// blocks [0, EB): deg/count atomics.  [EB, EB+CB): cast x,h0 -> bf16.
// [EB+CB, EB+CB+25): swizzle MFMA B fragments + bias.

constexpr int EB = (NE + 255) / 256;           // 3125
constexpr int XOCT = NN * CI / 8;              // 100000 bf16x8 octets in x
constexpr int HOCT = NN * CO / 8;              // 400000 octets in h0
constexpr int CB = (XOCT + HOCT + 255) / 256;  // 1954

__global__ void __launch_bounds__(256) k_deg_cast_prep(
    const int* __restrict__ src, const int* __restrict__ dst, const float* __restrict__ ew,
    float* __restrict__ deg, int* __restrict__ count,
    const float* __restrict__ x, const float* __restrict__ h0,
    __bf16* __restrict__ x_bf, __bf16* __restrict__ h0_bf,
    const float* __restrict__ Wx, const float* __restrict__ Wh,
    const float* __restrict__ bx, const float* __restrict__ bh,
    bf16x8* __restrict__ BfragZR, bf16x8* __restrict__ BfragHT, float* __restrict__ biasC) {
    int b = blockIdx.x;
    if (b < EB) {
        int e = b * 256 + threadIdx.x;
        if (e >= NE) return;
        int s = src[e], d = dst[e];
        float w = (s == d) ? 0.f : ew[e];
        atomicAdd(&deg[s], w);
        atomicAdd(&count[d], 1);
    } else if (b < EB + CB) {
        int t = (b - EB) * 256 + threadIdx.x;  // octet index
        const float* sp; __bf16* dp;
        if (t < XOCT) { sp = x + t * 8; dp = x_bf + t * 8; }
        else if (t < XOCT + HOCT) { int u = t - XOCT; sp = h0 + u * 8; dp = h0_bf + u * 8; }
        else return;
        float4 a = *(const float4*)sp;
        float4 c = *(const float4*)(sp + 4);
        bf16x8 o;
        o[0] = (__bf16)a.x; o[1] = (__bf16)a.y; o[2] = (__bf16)a.z; o[3] = (__bf16)a.w;
        o[4] = (__bf16)c.x; o[5] = (__bf16)c.y; o[6] = (__bf16)c.z; o[7] = (__bf16)c.w;
        *(bf16x8*)dp = o;
    } else {
        int tid = (b - EB - CB) * 256 + threadIdx.x;
        if (tid < 6144) {
            int e = tid, gate, n, kk, l;
            if (e < 4096) {
                int t = e >> 9, rem = e & 511;
                kk = rem >> 6; l = rem & 63;
                n = t * 16 + (l & 15);
                gate = n >> 6;
            } else {
                int e2 = e - 4096;
                int t = e2 >> 9, rem = e2 & 511;
                kk = rem >> 6; l = rem & 63;
                n = t * 16 + (l & 15);
                gate = 2;
            }
            int co = n & 63;
            int k0 = kk * 32 + (l >> 4) * 8;
            bf16x8 f;
#pragma unroll
            for (int j = 0; j < 8; j++) {
                int k = k0 + j;
                float w = 0.f;
                if (k < 48) w = Wx[((gate * 3 + (k >> 4)) * 16 + (k & 15)) * 64 + co];
                else if (k < 240) { int kh = k - 48; w = Wh[((gate * 3 + (kh >> 6)) * 64 + (kh & 63)) * 64 + co]; }
                f[j] = (__bf16)w;
            }
            if (e < 4096) BfragZR[e] = f; else BfragHT[e - 4096] = f;
        } else if (tid < 6144 + 192) {
            int i = tid - 6144;
            biasC[i] = bx[i] + bh[i];
        }
    }
}

// ============================= scan =============================

__global__ void k_scan1(const int* __restrict__ count, int* __restrict__ S, int* __restrict__ bsums) {
    __shared__ int ts[256];
    int tid = threadIdx.x;
    int base = blockIdx.x * 1024;
    int vals[4]; int s = 0;
#pragma unroll
    for (int j = 0; j < 4; j++) {
        int idx = base + tid * 4 + j;
        int v = (idx < NN) ? count[idx] : 0;
        s += v; vals[j] = s;
    }
    ts[tid] = s;
    __syncthreads();
    for (int off = 1; off < 256; off <<= 1) {
        int v = (tid >= off) ? ts[tid - off] : 0;
        __syncthreads();
        ts[tid] += v;
        __syncthreads();
    }
    int prev = (tid > 0) ? ts[tid - 1] : 0;
#pragma unroll
    for (int j = 0; j < 4; j++) {
        int idx = base + tid * 4 + j;
        if (idx < NN) S[idx] = vals[j] + prev;
    }
    if (tid == 255) bsums[blockIdx.x] = ts[255];
}

__global__ void k_scan2(int* __restrict__ bsums, int nb) {
    if (threadIdx.x == 0 && blockIdx.x == 0) {
        int run = 0;
        for (int i = 0; i < nb; i++) { int v = bsums[i]; bsums[i] = run; run += v; }
    }
}

// also computes dinv = deg > 0 ? rsqrt(deg) : 0  (in place on deg array)
__global__ void k_scan3_dinv(const int* __restrict__ S, const int* __restrict__ count,
                             const int* __restrict__ bsums,
                             int* __restrict__ fill, int* __restrict__ rowptr,
                             float* __restrict__ deg) {
    int i = blockIdx.x * 256 + threadIdx.x;
    if (i >= NN) return;
    int tot = S[i] + bsums[i >> 10];
    rowptr[i + 1] = tot;
    fill[i] = tot - count[i];
    if (i == 0) rowptr[0] = 0;
    float d = deg[i];
    deg[i] = (d > 0.f) ? (1.f / sqrtf(d)) : 0.f;
}

__global__ void k_scatter(const int* __restrict__ src, const int* __restrict__ dst,
                          const float* __restrict__ ew, const float* __restrict__ dinv,
                          int* __restrict__ fill, int2* __restrict__ csr_ew) {
    int e = blockIdx.x * 256 + threadIdx.x;
    if (e >= NE) return;
    int s = src[e], d = dst[e];
    float w = (s == d) ? 0.f : ew[e];
    float nw = -dinv[s] * w * dinv[d];
    int pos = atomicAdd(&fill[d], 1);
    csr_ew[pos] = make_int2(s, __float_as_int(nw));
}

// ============================= propagation (bf16 domain) =============================
// out[n][:] = scale * sum_{e in row n} w_e * v[src_e][:]  (- sub[n][:] if sub)

// C=64: wave per node; lane = 8*j + cg; 8 edges in flight, cg = bf16x8 group (16B).
__device__ inline void prop64_body(int n, int lane,
                                   const __bf16* __restrict__ v, const __bf16* __restrict__ sub,
                                   float scale, const int* __restrict__ rowptr,
                                   const int2* __restrict__ ew, __bf16* __restrict__ out) {
    int j = lane >> 3, cg = lane & 7;
    int beg = rowptr[n], end = rowptr[n + 1];
    float acc[8] = {0.f, 0.f, 0.f, 0.f, 0.f, 0.f, 0.f, 0.f};
    for (int e = beg + j; e < end; e += 8) {
        int2 p = ew[e];
        float w = __int_as_float(p.y);
        uint4 u = *(const uint4*)((const char*)v + ((size_t)p.x * 128 + cg * 16));
        acc[0] += w * blo(u.x); acc[1] += w * bhi(u.x);
        acc[2] += w * blo(u.y); acc[3] += w * bhi(u.y);
        acc[4] += w * blo(u.z); acc[5] += w * bhi(u.z);
        acc[6] += w * blo(u.w); acc[7] += w * bhi(u.w);
    }
#pragma unroll
    for (int m = 8; m <= 32; m <<= 1) {
#pragma unroll
        for (int i = 0; i < 8; i++) acc[i] += __shfl_xor(acc[i], m, 64);
    }
    if (lane < 8) {
        float o[8];
        if (sub) {
            uint4 su = *(const uint4*)((const char*)sub + ((size_t)n * 128 + lane * 16));
            o[0] = scale * acc[0] - blo(su.x); o[1] = scale * acc[1] - bhi(su.x);
            o[2] = scale * acc[2] - blo(su.y); o[3] = scale * acc[3] - bhi(su.y);
            o[4] = scale * acc[4] - blo(su.z); o[5] = scale * acc[5] - bhi(su.z);
            o[6] = scale * acc[6] - blo(su.w); o[7] = scale * acc[7] - bhi(su.w);
        } else {
#pragma unroll
            for (int i = 0; i < 8; i++) o[i] = scale * acc[i];
        }
        bf16x8 st;
#pragma unroll
        for (int i = 0; i < 8; i++) st[i] = (__bf16)o[i];
        *(bf16x8*)(out + (size_t)n * 64 + lane * 8) = st;
    }
}

// C=16: wave per node; lane = 2*j + cg; 32 edges in flight, row = 2 x 16B.
__device__ inline void prop16_body(int n, int lane,
                                   const __bf16* __restrict__ v, const __bf16* __restrict__ sub,
                                   float scale, const int* __restrict__ rowptr,
                                   const int2* __restrict__ ew, __bf16* __restrict__ out) {
    int j = lane >> 1, cg = lane & 1;
    int beg = rowptr[n], end = rowptr[n + 1];
    float acc[8] = {0.f, 0.f, 0.f, 0.f, 0.f, 0.f, 0.f, 0.f};
    for (int e = beg + j; e < end; e += 32) {
        int2 p = ew[e];
        float w = __int_as_float(p.y);
        uint4 u = *(const uint4*)((const char*)v + ((size_t)p.x * 32 + cg * 16));
        acc[0] += w * blo(u.x); acc[1] += w * bhi(u.x);
        acc[2] += w * blo(u.y); acc[3] += w * bhi(u.y);
        acc[4] += w * blo(u.z); acc[5] += w * bhi(u.z);
        acc[6] += w * blo(u.w); acc[7] += w * bhi(u.w);
    }
#pragma unroll
    for (int m = 2; m <= 32; m <<= 1) {
#pragma unroll
        for (int i = 0; i < 8; i++) acc[i] += __shfl_xor(acc[i], m, 64);
    }
    if (lane < 2) {
        float o[8];
        if (sub) {
            uint4 su = *(const uint4*)((const char*)sub + ((size_t)n * 32 + lane * 16));
            o[0] = scale * acc[0] - blo(su.x); o[1] = scale * acc[1] - bhi(su.x);
            o[2] = scale * acc[2] - blo(su.y); o[3] = scale * acc[3] - bhi(su.y);
            o[4] = scale * acc[4] - blo(su.z); o[5] = scale * acc[5] - bhi(su.z);
            o[6] = scale * acc[6] - blo(su.w); o[7] = scale * acc[7] - bhi(su.w);
        } else {
#pragma unroll
            for (int i = 0; i < 8; i++) o[i] = scale * acc[i];
        }
        bf16x8 st;
#pragma unroll
        for (int i = 0; i < 8; i++) st[i] = (__bf16)o[i];
        *(bf16x8*)(out + (size_t)n * 16 + lane * 8) = st;
    }
}

// fused stage: waves [0,50000) do h-prop (C=64), waves [50000,100000) do x-prop (C=16)
__global__ void __launch_bounds__(256) k_stage(
    const __bf16* __restrict__ vh, const __bf16* __restrict__ subh, float sh,
    const __bf16* __restrict__ vx, const __bf16* __restrict__ subx, float sx,
    const int* __restrict__ rowptr, const int2* __restrict__ ew,
    __bf16* __restrict__ outh, __bf16* __restrict__ outx) {
    int gw = blockIdx.x * 4 + (threadIdx.x >> 6);
    int lane = threadIdx.x & 63;
    if (gw < NN) prop64_body(gw, lane, vh, subh, sh, rowptr, ew, outh);
    else prop16_body(gw - NN, lane, vx, subx, sx, rowptr, ew, outx);
}

__global__ void __launch_bounds__(256) k_prop64(
    const __bf16* __restrict__ v, const __bf16* __restrict__ sub, float scale,
    const int* __restrict__ rowptr, const int2* __restrict__ ew, __bf16* __restrict__ out) {
    int n = blockIdx.x * 4 + (threadIdx.x >> 6);
    if (n >= NN) return;
    prop64_body(n, threadIdx.x & 63, v, sub, scale, rowptr, ew, out);
}

// ============================= MFMA dense gates =============================
// Logical A row (K=256): [x(16)|Tx1(16)|Tx2(16)|h(64)|Th1(64)|Th2(64)|pad(16)], all bf16.

__device__ inline bf16x8 load_a_bf(int c, int m,
                                   const __bf16* __restrict__ xb, const __bf16* __restrict__ t1,
                                   const __bf16* __restrict__ t2, const __bf16* __restrict__ hb,
                                   const __bf16* __restrict__ h1, const __bf16* __restrict__ h2) {
    if (c >= 30) {
        bf16x8 a;
#pragma unroll
        for (int j = 0; j < 8; j++) a[j] = (__bf16)0.f;
        return a;
    }
    if (c < 6) {
        const __bf16* base = (c < 2) ? xb : ((c < 4) ? t1 : t2);
        return *(const bf16x8*)(base + (size_t)m * 16 + (c & 1) * 8);
    }
    int d = c - 6;
    const __bf16* base = (d < 8) ? hb : ((d < 16) ? h1 : h2);
    return *(const bf16x8*)(base + (size_t)m * 64 + (d & 7) * 8);
}

// z and r gates: one wave per 16-node tile, 128 output cols (8 out-tiles).
__global__ void __launch_bounds__(256) k_mfma_zr(
    const __bf16* __restrict__ xb, const __bf16* __restrict__ t1, const __bf16* __restrict__ t2,
    const __bf16* __restrict__ hb, const __bf16* __restrict__ h1, const __bf16* __restrict__ h2,
    const bf16x8* __restrict__ Bfrag, const float* __restrict__ biasC,
    const float* __restrict__ h0, float* __restrict__ z, __bf16* __restrict__ hr_bf) {
    int wv = (blockIdx.x * 256 + threadIdx.x) >> 6;
    if (wv >= NN / 16) return;
    int lane = threadIdx.x & 63;
    int q = lane >> 4, r16 = lane & 15;
    int ma = wv * 16 + r16;
    f32x4 acc[8];
#pragma unroll
    for (int t = 0; t < 8; t++) acc[t] = (f32x4){0.f, 0.f, 0.f, 0.f};
#pragma unroll
    for (int kk = 0; kk < 8; kk++) {
        bf16x8 a = load_a_bf(kk * 4 + q, ma, xb, t1, t2, hb, h1, h2);
#pragma unroll
        for (int t = 0; t < 8; t++)
            acc[t] = __builtin_amdgcn_mfma_f32_16x16x32_bf16(a, Bfrag[(t * 8 + kk) * 64 + lane], acc[t], 0, 0, 0);
    }
    int mbase = wv * 16 + q * 4;
#pragma unroll
    for (int t = 0; t < 8; t++) {
        int co = t * 16 + r16;      // 0..127
        float bias = biasC[co];
        int col = co & 63;
#pragma unroll
        for (int reg = 0; reg < 4; reg++) {
            int mm = mbase + reg;
            float p = acc[t][reg] + bias;
            float s = 1.f / (1.f + __expf(-p));
            if (t < 4) z[(size_t)mm * 64 + col] = s;
            else       hr_bf[(size_t)mm * 64 + col] = (__bf16)(s * h0[(size_t)mm * 64 + col]);
        }
    }
}

// htilde gate + GRU combine: one wave per 16-node tile, 64 output cols (4 out-tiles).
__global__ void __launch_bounds__(256) k_mfma_ht(
    const __bf16* __restrict__ xb, const __bf16* __restrict__ t1, const __bf16* __restrict__ t2,
    const __bf16* __restrict__ hrb, const __bf16* __restrict__ r1, const __bf16* __restrict__ r2,
    const bf16x8* __restrict__ Bfrag, const float* __restrict__ biasC,
    const float* __restrict__ z, const float* __restrict__ h0,
    float* __restrict__ hout) {
    int wv = (blockIdx.x * 256 + threadIdx.x) >> 6;
    if (wv >= NN / 16) return;
    int lane = threadIdx.x & 63;
    int q = lane >> 4, r16 = lane & 15;
    int ma = wv * 16 + r16;
    f32x4 acc[4];
#pragma unroll
    for (int t = 0; t < 4; t++) acc[t] = (f32x4){0.f, 0.f, 0.f, 0.f};
#pragma unroll
    for (int kk = 0; kk < 8; kk++) {
        bf16x8 a = load_a_bf(kk * 4 + q, ma, xb, t1, t2, hrb, r1, r2);
#pragma unroll
        for (int t = 0; t < 4; t++)
            acc[t] = __builtin_amdgcn_mfma_f32_16x16x32_bf16(a, Bfrag[(t * 8 + kk) * 64 + lane], acc[t], 0, 0, 0);
    }
    int mbase = wv * 16 + q * 4;
#pragma unroll
    for (int t = 0; t < 4; t++) {
        int co = t * 16 + r16;   // 0..63
        float bias = biasC[128 + co];
#pragma unroll
        for (int reg = 0; reg < 4; reg++) {
            int mm = mbase + reg;
            float p = acc[t][reg] + bias;
            float htl = tanhf(p);
            float zv = z[(size_t)mm * 64 + co];
            float h0v = h0[(size_t)mm * 64 + co];
            hout[(size_t)mm * 64 + co] = zv * h0v + (1.f - zv) * htl;
        }
    }
}

// y = relu(h) @ Wlin + blin
__global__ void k_ylin(const float* __restrict__ h, const float* __restrict__ Wlin,
                       const float* __restrict__ blin, float* __restrict__ y) {
    int t = blockIdx.x * 256 + threadIdx.x;
    int n = t >> 3, d = t & 7;
    if (n >= NN || d >= DD) return;
    float acc = blin[d];
#pragma unroll 8
    for (int c = 0; c < 64; c++) acc += fmaxf(h[n * 64 + c], 0.f) * Wlin[c * DD + d];
    y[n * DD + d] = acc;
}

// ============================= launch =============================

extern "C" void kernel_launch(void* const* d_in, const int* in_sizes, int n_in,
                              void* d_out, int out_size, void* d_ws, size_t ws_size,
                              hipStream_t stream) {
    (void)in_sizes; (void)n_in; (void)out_size; (void)ws_size;
    const float* x    = (const float*)d_in[0];
    const int*   eidx = (const int*)d_in[1];
    const float* ew   = (const float*)d_in[2];
    const float* h0   = (const float*)d_in[3];
    const float* Wx   = (const float*)d_in[4];
    const float* Wh   = (const float*)d_in[5];
    const float* bx   = (const float*)d_in[6];
    const float* bh   = (const float*)d_in[7];
    const float* Wlin = (const float*)d_in[8];
    const float* blin = (const float*)d_in[9];
    const int* src = eidx;
    const int* dst = eidx + NE;

    char* ws = (char*)d_ws;
    size_t off = 0;
    auto alloc = [&](size_t nbytes) -> void* {
        void* p = ws + off;
        off += (nbytes + 255) & ~(size_t)255;
        return p;
    };
    float*  dinv    = (float*)alloc(NN * 4);        // deg, then dinv in-place
    int*    count   = (int*)alloc(NN * 4);
    int*    S       = (int*)alloc(NN * 4);
    int*    fill    = (int*)alloc(NN * 4);
    int*    rowptr  = (int*)alloc((NN + 1) * 4);
    int*    bsums   = (int*)alloc(64 * 4);
    int2*   csr_ew  = (int2*)alloc((size_t)NE * 8);
    __bf16* x_bf    = (__bf16*)alloc((size_t)NN * CI * 2);
    __bf16* h0_bf   = (__bf16*)alloc((size_t)NN * CO * 2);
    __bf16* Tx1     = (__bf16*)alloc((size_t)NN * CI * 2);
    __bf16* Tx2     = (__bf16*)alloc((size_t)NN * CI * 2);
    __bf16* Th1     = (__bf16*)alloc((size_t)NN * CO * 2);
    __bf16* Th2     = (__bf16*)alloc((size_t)NN * CO * 2);
    __bf16* hr_bf   = (__bf16*)alloc((size_t)NN * CO * 2);
    float*  z       = (float*)alloc((size_t)NN * CO * 4);
    bf16x8* BfragZR = (bf16x8*)alloc(4096 * 16);
    bf16x8* BfragHT = (bf16x8*)alloc(2048 * 16);
    float*  biasC   = (float*)alloc(192 * 4);

    float* hout = (float*)d_out;
    float* yout = hout + (size_t)NN * CO;

    constexpr int NB = (NN + 1023) / 1024;   // scan chunks
    const int NBLK = (NN + 255) / 256;
    const int PROPB = (NN + 3) / 4;          // 4 waves/block, wave per node
    const int STAGEB = (2 * NN + 3) / 4;     // fused h+x stage
    const int GEMMB = (NN / 16 * 64 + 255) / 256;

    hipMemsetAsync(dinv, 0, NN * 4, stream);
    hipMemsetAsync(count, 0, NN * 4, stream);

    k_deg_cast_prep<<<EB + CB + 25, 256, 0, stream>>>(
        src, dst, ew, dinv, count, x, h0, x_bf, h0_bf,
        Wx, Wh, bx, bh, BfragZR, BfragHT, biasC);
    k_scan1<<<NB, 256, 0, stream>>>(count, S, bsums);
    k_scan2<<<1, 64, 0, stream>>>(bsums, NB);
    k_scan3_dinv<<<NBLK, 256, 0, stream>>>(S, count, bsums, fill, rowptr, dinv);
    k_scatter<<<EB, 256, 0, stream>>>(src, dst, ew, dinv, fill, csr_ew);

    // stage 1: Th1 = P(h0), Tx1 = P(x)
    k_stage<<<STAGEB, 256, 0, stream>>>(h0_bf, nullptr, 1.f, x_bf, nullptr, 1.f,
                                        rowptr, csr_ew, Th1, Tx1);
    // stage 2: Th2 = 2P(Th1) - h0, Tx2 = 2P(Tx1) - x
    k_stage<<<STAGEB, 256, 0, stream>>>(Th1, h0_bf, 2.f, Tx1, x_bf, 2.f,
                                        rowptr, csr_ew, Th2, Tx2);

    // z and r gates (r fused into hr = r*h0)
    k_mfma_zr<<<GEMMB, 256, 0, stream>>>(x_bf, Tx1, Tx2, h0_bf, Th1, Th2,
                                         BfragZR, biasC, h0, z, hr_bf);
    // propagate hr (reuse Th1/Th2 as Thr1/Thr2)
    k_prop64<<<PROPB, 256, 0, stream>>>(hr_bf, nullptr, 1.f, rowptr, csr_ew, Th1);
    k_prop64<<<PROPB, 256, 0, stream>>>(Th1, hr_bf, 2.f, rowptr, csr_ew, Th2);
    // htilde gate + GRU combine -> h (written directly to d_out)
    k_mfma_ht<<<GEMMB, 256, 0, stream>>>(x_bf, Tx1, Tx2, hr_bf, Th1, Th2,
                                         BfragHT, biasC, z, h0, hout);
    // decoder
    k_ylin<<<(NN * 8 + 255) / 256, 256, 0, stream>>>(hout, Wlin, blin, yout);
}

// Round 4
// 381.085 us; speedup vs baseline: 2.3747x; 1.0285x over previous
//
#include <hip/hip_runtime.h>

// Problem constants (from reference)
constexpr int NN = 50000;   // nodes
constexpr int NE = 800000;  // edges
constexpr int CI = 16;      // in channels
constexpr int CO = 64;      // out channels
constexpr int DD = 7;       // decoder dim

typedef __bf16 bf16x8 __attribute__((ext_vector_type(8)));
typedef float  f32x4  __attribute__((ext_vector_type(4)));

__device__ inline float blo(unsigned u) { return __uint_as_float(u << 16); }
__device__ inline float bhi(unsigned u) { return __uint_as_float(u & 0xffff0000u); }

// ================= fused: edge histograms(+rank) + bf16 casts + B-prep =================
// blocks [0, EB): deg atomics + count atomics (rank capture).
// [EB, EB+CB): cast x,h0 -> bf16.  [EB+CB, EB+CB+25): MFMA B fragments + bias.

constexpr int EB = (NE + 255) / 256;           // 3125
constexpr int XOCT = NN * CI / 8;              // 100000 bf16x8 octets in x
constexpr int HOCT = NN * CO / 8;              // 400000 octets in h0
constexpr int CB = (XOCT + HOCT + 255) / 256;  // 1954

__global__ void __launch_bounds__(256) k_deg_cast_prep(
    const int* __restrict__ src, const int* __restrict__ dst, const float* __restrict__ ew,
    float* __restrict__ deg, int* __restrict__ count, int* __restrict__ rank,
    const float* __restrict__ x, const float* __restrict__ h0,
    __bf16* __restrict__ x_bf, __bf16* __restrict__ h0_bf,
    const float* __restrict__ Wx, const float* __restrict__ Wh,
    const float* __restrict__ bx, const float* __restrict__ bh,
    bf16x8* __restrict__ BfragZR, bf16x8* __restrict__ BfragHT, float* __restrict__ biasC) {
    int b = blockIdx.x;
    if (b < EB) {
        int e = b * 256 + threadIdx.x;
        if (e >= NE) return;
        int s = src[e], d = dst[e];
        float w = (s == d) ? 0.f : ew[e];
        atomicAdd(&deg[s], w);
        rank[e] = atomicAdd(&count[d], 1);   // rank doubles as placement slot
    } else if (b < EB + CB) {
        int t = (b - EB) * 256 + threadIdx.x;  // octet index
        const float* sp; __bf16* dp;
        if (t < XOCT) { sp = x + t * 8; dp = x_bf + t * 8; }
        else if (t < XOCT + HOCT) { int u = t - XOCT; sp = h0 + u * 8; dp = h0_bf + u * 8; }
        else return;
        float4 a = *(const float4*)sp;
        float4 c = *(const float4*)(sp + 4);
        bf16x8 o;
        o[0] = (__bf16)a.x; o[1] = (__bf16)a.y; o[2] = (__bf16)a.z; o[3] = (__bf16)a.w;
        o[4] = (__bf16)c.x; o[5] = (__bf16)c.y; o[6] = (__bf16)c.z; o[7] = (__bf16)c.w;
        *(bf16x8*)dp = o;
    } else {
        int tid = (b - EB - CB) * 256 + threadIdx.x;
        if (tid < 6144) {
            int e = tid, gate, n, kk, l;
            if (e < 4096) {
                int t = e >> 9, rem = e & 511;
                kk = rem >> 6; l = rem & 63;
                n = t * 16 + (l & 15);
                gate = n >> 6;
            } else {
                int e2 = e - 4096;
                int t = e2 >> 9, rem = e2 & 511;
                kk = rem >> 6; l = rem & 63;
                n = t * 16 + (l & 15);
                gate = 2;
            }
            int co = n & 63;
            int k0 = kk * 32 + (l >> 4) * 8;
            bf16x8 f;
#pragma unroll
            for (int j = 0; j < 8; j++) {
                int k = k0 + j;
                float w = 0.f;
                if (k < 48) w = Wx[((gate * 3 + (k >> 4)) * 16 + (k & 15)) * 64 + co];
                else if (k < 240) { int kh = k - 48; w = Wh[((gate * 3 + (kh >> 6)) * 64 + (kh & 63)) * 64 + co]; }
                f[j] = (__bf16)w;
            }
            if (e < 4096) BfragZR[e] = f; else BfragHT[e - 4096] = f;
        } else if (tid < 6144 + 192) {
            int i = tid - 6144;
            biasC[i] = bx[i] + bh[i];
        }
    }
}

// ============================= scan =============================

__global__ void k_scan1(const int* __restrict__ count, int* __restrict__ S, int* __restrict__ bsums) {
    __shared__ int ts[256];
    int tid = threadIdx.x;
    int base = blockIdx.x * 1024;
    int vals[4]; int s = 0;
#pragma unroll
    for (int j = 0; j < 4; j++) {
        int idx = base + tid * 4 + j;
        int v = (idx < NN) ? count[idx] : 0;
        s += v; vals[j] = s;
    }
    ts[tid] = s;
    __syncthreads();
    for (int off = 1; off < 256; off <<= 1) {
        int v = (tid >= off) ? ts[tid - off] : 0;
        __syncthreads();
        ts[tid] += v;
        __syncthreads();
    }
    int prev = (tid > 0) ? ts[tid - 1] : 0;
#pragma unroll
    for (int j = 0; j < 4; j++) {
        int idx = base + tid * 4 + j;
        if (idx < NN) S[idx] = vals[j] + prev;
    }
    if (tid == 255) bsums[blockIdx.x] = ts[255];
}

__global__ void k_scan2(int* __restrict__ bsums, int nb) {
    if (threadIdx.x == 0 && blockIdx.x == 0) {
        int run = 0;
        for (int i = 0; i < nb; i++) { int v = bsums[i]; bsums[i] = run; run += v; }
    }
}

// rowptr from scan pieces; dinv = deg > 0 ? rsqrt(deg) : 0 (in place on deg)
__global__ void k_scan3_dinv(const int* __restrict__ S, const int* __restrict__ count,
                             const int* __restrict__ bsums,
                             int* __restrict__ rowptr, float* __restrict__ deg) {
    int i = blockIdx.x * 256 + threadIdx.x;
    if (i >= NN) return;
    int tot = S[i] + bsums[i >> 10];
    rowptr[i + 1] = tot;
    if (i == 0) rowptr[0] = 0;
    float d = deg[i];
    deg[i] = (d > 0.f) ? (1.f / sqrtf(d)) : 0.f;
}

// atomic-free CSR placement using captured ranks
__global__ void k_place(const int* __restrict__ src, const int* __restrict__ dst,
                        const float* __restrict__ ew, const int* __restrict__ rank,
                        const float* __restrict__ dinv, const int* __restrict__ rowptr,
                        int2* __restrict__ csr_ew) {
    int e = blockIdx.x * 256 + threadIdx.x;
    if (e >= NE) return;
    int s = src[e], d = dst[e];
    float w = (s == d) ? 0.f : ew[e];
    float nw = -dinv[s] * w * dinv[d];
    csr_ew[rowptr[d] + rank[e]] = make_int2(s, __float_as_int(nw));
}

// ============================= propagation (bf16 domain) =============================
// out[n][:] = scale * sum_{e in row n} w_e * v[src_e][:]  (- sub[n][:] if sub)

// C=64: wave per node; lane = 8*j + cg; 8 edges in flight, cg = bf16x8 group (16B).
__device__ inline void prop64_body(int n, int lane,
                                   const __bf16* __restrict__ v, const __bf16* __restrict__ sub,
                                   float scale, const int* __restrict__ rowptr,
                                   const int2* __restrict__ ew, __bf16* __restrict__ out) {
    int j = lane >> 3, cg = lane & 7;
    int beg = rowptr[n], end = rowptr[n + 1];
    float acc[8] = {0.f, 0.f, 0.f, 0.f, 0.f, 0.f, 0.f, 0.f};
    for (int e = beg + j; e < end; e += 8) {
        int2 p = ew[e];
        float w = __int_as_float(p.y);
        uint4 u = *(const uint4*)((const char*)v + ((size_t)p.x * 128 + cg * 16));
        acc[0] += w * blo(u.x); acc[1] += w * bhi(u.x);
        acc[2] += w * blo(u.y); acc[3] += w * bhi(u.y);
        acc[4] += w * blo(u.z); acc[5] += w * bhi(u.z);
        acc[6] += w * blo(u.w); acc[7] += w * bhi(u.w);
    }
#pragma unroll
    for (int m = 8; m <= 32; m <<= 1) {
#pragma unroll
        for (int i = 0; i < 8; i++) acc[i] += __shfl_xor(acc[i], m, 64);
    }
    if (lane < 8) {
        float o[8];
        if (sub) {
            uint4 su = *(const uint4*)((const char*)sub + ((size_t)n * 128 + lane * 16));
            o[0] = scale * acc[0] - blo(su.x); o[1] = scale * acc[1] - bhi(su.x);
            o[2] = scale * acc[2] - blo(su.y); o[3] = scale * acc[3] - bhi(su.y);
            o[4] = scale * acc[4] - blo(su.z); o[5] = scale * acc[5] - bhi(su.z);
            o[6] = scale * acc[6] - blo(su.w); o[7] = scale * acc[7] - bhi(su.w);
        } else {
#pragma unroll
            for (int i = 0; i < 8; i++) o[i] = scale * acc[i];
        }
        bf16x8 st;
#pragma unroll
        for (int i = 0; i < 8; i++) st[i] = (__bf16)o[i];
        *(bf16x8*)(out + (size_t)n * 64 + lane * 8) = st;
    }
}

// C=16: wave per node; lane = 2*j + cg; 32 edges in flight, row = 2 x 16B.
__device__ inline void prop16_body(int n, int lane,
                                   const __bf16* __restrict__ v, const __bf16* __restrict__ sub,
                                   float scale, const int* __restrict__ rowptr,
                                   const int2* __restrict__ ew, __bf16* __restrict__ out) {
    int j = lane >> 1, cg = lane & 1;
    int beg = rowptr[n], end = rowptr[n + 1];
    float acc[8] = {0.f, 0.f, 0.f, 0.f, 0.f, 0.f, 0.f, 0.f};
    for (int e = beg + j; e < end; e += 32) {
        int2 p = ew[e];
        float w = __int_as_float(p.y);
        uint4 u = *(const uint4*)((const char*)v + ((size_t)p.x * 32 + cg * 16));
        acc[0] += w * blo(u.x); acc[1] += w * bhi(u.x);
        acc[2] += w * blo(u.y); acc[3] += w * bhi(u.y);
        acc[4] += w * blo(u.z); acc[5] += w * bhi(u.z);
        acc[6] += w * blo(u.w); acc[7] += w * bhi(u.w);
    }
#pragma unroll
    for (int m = 2; m <= 32; m <<= 1) {
#pragma unroll
        for (int i = 0; i < 8; i++) acc[i] += __shfl_xor(acc[i], m, 64);
    }
    if (lane < 2) {
        float o[8];
        if (sub) {
            uint4 su = *(const uint4*)((const char*)sub + ((size_t)n * 32 + lane * 16));
            o[0] = scale * acc[0] - blo(su.x); o[1] = scale * acc[1] - bhi(su.x);
            o[2] = scale * acc[2] - blo(su.y); o[3] = scale * acc[3] - bhi(su.y);
            o[4] = scale * acc[4] - blo(su.z); o[5] = scale * acc[5] - bhi(su.z);
            o[6] = scale * acc[6] - blo(su.w); o[7] = scale * acc[7] - bhi(su.w);
        } else {
#pragma unroll
            for (int i = 0; i < 8; i++) o[i] = scale * acc[i];
        }
        bf16x8 st;
#pragma unroll
        for (int i = 0; i < 8; i++) st[i] = (__bf16)o[i];
        *(bf16x8*)(out + (size_t)n * 16 + lane * 8) = st;
    }
}

// fused stage: waves [0,50000) do h-prop (C=64), waves [50000,100000) do x-prop (C=16)
__global__ void __launch_bounds__(256) k_stage(
    const __bf16* __restrict__ vh, const __bf16* __restrict__ subh, float sh,
    const __bf16* __restrict__ vx, const __bf16* __restrict__ subx, float sx,
    const int* __restrict__ rowptr, const int2* __restrict__ ew,
    __bf16* __restrict__ outh, __bf16* __restrict__ outx) {
    int gw = blockIdx.x * 4 + (threadIdx.x >> 6);
    int lane = threadIdx.x & 63;
    if (gw < NN) prop64_body(gw, lane, vh, subh, sh, rowptr, ew, outh);
    else prop16_body(gw - NN, lane, vx, subx, sx, rowptr, ew, outx);
}

__global__ void __launch_bounds__(256) k_prop64(
    const __bf16* __restrict__ v, const __bf16* __restrict__ sub, float scale,
    const int* __restrict__ rowptr, const int2* __restrict__ ew, __bf16* __restrict__ out) {
    int n = blockIdx.x * 4 + (threadIdx.x >> 6);
    if (n >= NN) return;
    prop64_body(n, threadIdx.x & 63, v, sub, scale, rowptr, ew, out);
}

// ============================= MFMA dense gates =============================
// Logical A row (K=256): [x(16)|Tx1(16)|Tx2(16)|h(64)|Th1(64)|Th2(64)|pad(16)], all bf16.

__device__ inline bf16x8 load_a_bf(int c, int m,
                                   const __bf16* __restrict__ xb, const __bf16* __restrict__ t1,
                                   const __bf16* __restrict__ t2, const __bf16* __restrict__ hb,
                                   const __bf16* __restrict__ h1, const __bf16* __restrict__ h2) {
    if (c >= 30) {
        bf16x8 a;
#pragma unroll
        for (int j = 0; j < 8; j++) a[j] = (__bf16)0.f;
        return a;
    }
    if (c < 6) {
        const __bf16* base = (c < 2) ? xb : ((c < 4) ? t1 : t2);
        return *(const bf16x8*)(base + (size_t)m * 16 + (c & 1) * 8);
    }
    int d = c - 6;
    const __bf16* base = (d < 8) ? hb : ((d < 16) ? h1 : h2);
    return *(const bf16x8*)(base + (size_t)m * 64 + (d & 7) * 8);
}

// z and r gates: one wave per 16-node tile, 128 output cols (8 out-tiles).
__global__ void __launch_bounds__(256) k_mfma_zr(
    const __bf16* __restrict__ xb, const __bf16* __restrict__ t1, const __bf16* __restrict__ t2,
    const __bf16* __restrict__ hb, const __bf16* __restrict__ h1, const __bf16* __restrict__ h2,
    const bf16x8* __restrict__ Bfrag, const float* __restrict__ biasC,
    const float* __restrict__ h0, __bf16* __restrict__ z_bf, __bf16* __restrict__ hr_bf) {
    int wv = (blockIdx.x * 256 + threadIdx.x) >> 6;
    if (wv >= NN / 16) return;
    int lane = threadIdx.x & 63;
    int q = lane >> 4, r16 = lane & 15;
    int ma = wv * 16 + r16;
    f32x4 acc[8];
#pragma unroll
    for (int t = 0; t < 8; t++) acc[t] = (f32x4){0.f, 0.f, 0.f, 0.f};
#pragma unroll
    for (int kk = 0; kk < 8; kk++) {
        bf16x8 a = load_a_bf(kk * 4 + q, ma, xb, t1, t2, hb, h1, h2);
#pragma unroll
        for (int t = 0; t < 8; t++)
            acc[t] = __builtin_amdgcn_mfma_f32_16x16x32_bf16(a, Bfrag[(t * 8 + kk) * 64 + lane], acc[t], 0, 0, 0);
    }
    int mbase = wv * 16 + q * 4;
#pragma unroll
    for (int t = 0; t < 8; t++) {
        int co = t * 16 + r16;      // 0..127
        float bias = biasC[co];
        int col = co & 63;
#pragma unroll
        for (int reg = 0; reg < 4; reg++) {
            int mm = mbase + reg;
            float p = acc[t][reg] + bias;
            float s = 1.f / (1.f + __expf(-p));
            if (t < 4) z_bf[(size_t)mm * 64 + col] = (__bf16)s;
            else       hr_bf[(size_t)mm * 64 + col] = (__bf16)(s * h0[(size_t)mm * 64 + col]);
        }
    }
}

// htilde gate + GRU combine: one wave per 16-node tile, 64 output cols (4 out-tiles).
__global__ void __launch_bounds__(256) k_mfma_ht(
    const __bf16* __restrict__ xb, const __bf16* __restrict__ t1, const __bf16* __restrict__ t2,
    const __bf16* __restrict__ hrb, const __bf16* __restrict__ r1, const __bf16* __restrict__ r2,
    const bf16x8* __restrict__ Bfrag, const float* __restrict__ biasC,
    const __bf16* __restrict__ z_bf, const float* __restrict__ h0,
    float* __restrict__ hout) {
    int wv = (blockIdx.x * 256 + threadIdx.x) >> 6;
    if (wv >= NN / 16) return;
    int lane = threadIdx.x & 63;
    int q = lane >> 4, r16 = lane & 15;
    int ma = wv * 16 + r16;
    f32x4 acc[4];
#pragma unroll
    for (int t = 0; t < 4; t++) acc[t] = (f32x4){0.f, 0.f, 0.f, 0.f};
#pragma unroll
    for (int kk = 0; kk < 8; kk++) {
        bf16x8 a = load_a_bf(kk * 4 + q, ma, xb, t1, t2, hrb, r1, r2);
#pragma unroll
        for (int t = 0; t < 4; t++)
            acc[t] = __builtin_amdgcn_mfma_f32_16x16x32_bf16(a, Bfrag[(t * 8 + kk) * 64 + lane], acc[t], 0, 0, 0);
    }
    int mbase = wv * 16 + q * 4;
#pragma unroll
    for (int t = 0; t < 4; t++) {
        int co = t * 16 + r16;   // 0..63
        float bias = biasC[128 + co];
#pragma unroll
        for (int reg = 0; reg < 4; reg++) {
            int mm = mbase + reg;
            float p = acc[t][reg] + bias;
            float htl = tanhf(p);
            float zv = (float)z_bf[(size_t)mm * 64 + co];
            float h0v = h0[(size_t)mm * 64 + co];
            hout[(size_t)mm * 64 + co] = zv * h0v + (1.f - zv) * htl;
        }
    }
}

// y = relu(h) @ Wlin + blin
__global__ void k_ylin(const float* __restrict__ h, const float* __restrict__ Wlin,
                       const float* __restrict__ blin, float* __restrict__ y) {
    int t = blockIdx.x * 256 + threadIdx.x;
    int n = t >> 3, d = t & 7;
    if (n >= NN || d >= DD) return;
    float acc = blin[d];
#pragma unroll 8
    for (int c = 0; c < 64; c++) acc += fmaxf(h[n * 64 + c], 0.f) * Wlin[c * DD + d];
    y[n * DD + d] = acc;
}

// ============================= launch =============================

extern "C" void kernel_launch(void* const* d_in, const int* in_sizes, int n_in,
                              void* d_out, int out_size, void* d_ws, size_t ws_size,
                              hipStream_t stream) {
    (void)in_sizes; (void)n_in; (void)out_size; (void)ws_size;
    const float* x    = (const float*)d_in[0];
    const int*   eidx = (const int*)d_in[1];
    const float* ew   = (const float*)d_in[2];
    const float* h0   = (const float*)d_in[3];
    const float* Wx   = (const float*)d_in[4];
    const float* Wh   = (const float*)d_in[5];
    const float* bx   = (const float*)d_in[6];
    const float* bh   = (const float*)d_in[7];
    const float* Wlin = (const float*)d_in[8];
    const float* blin = (const float*)d_in[9];
    const int* src = eidx;
    const int* dst = eidx + NE;

    char* ws = (char*)d_ws;
    size_t off = 0;
    auto alloc = [&](size_t nbytes) -> void* {
        void* p = ws + off;
        off += (nbytes + 255) & ~(size_t)255;
        return p;
    };
    float*  dinv    = (float*)alloc(NN * 4);        // deg, then dinv in-place
    int*    count   = (int*)alloc(NN * 4);
    int*    S       = (int*)alloc(NN * 4);
    int*    rowptr  = (int*)alloc((NN + 1) * 4);
    int*    bsums   = (int*)alloc(64 * 4);
    int*    rank    = (int*)alloc((size_t)NE * 4);
    int2*   csr_ew  = (int2*)alloc((size_t)NE * 8);
    __bf16* x_bf    = (__bf16*)alloc((size_t)NN * CI * 2);
    __bf16* h0_bf   = (__bf16*)alloc((size_t)NN * CO * 2);
    __bf16* Tx1     = (__bf16*)alloc((size_t)NN * CI * 2);
    __bf16* Tx2     = (__bf16*)alloc((size_t)NN * CI * 2);
    __bf16* Th1     = (__bf16*)alloc((size_t)NN * CO * 2);
    __bf16* Th2     = (__bf16*)alloc((size_t)NN * CO * 2);
    __bf16* hr_bf   = (__bf16*)alloc((size_t)NN * CO * 2);
    __bf16* z_bf    = (__bf16*)alloc((size_t)NN * CO * 2);
    bf16x8* BfragZR = (bf16x8*)alloc(4096 * 16);
    bf16x8* BfragHT = (bf16x8*)alloc(2048 * 16);
    float*  biasC   = (float*)alloc(192 * 4);

    float* hout = (float*)d_out;
    float* yout = hout + (size_t)NN * CO;

    constexpr int NB = (NN + 1023) / 1024;   // scan chunks
    const int NBLK = (NN + 255) / 256;
    const int PROPB = (NN + 3) / 4;          // 4 waves/block, wave per node
    const int STAGEB = (2 * NN + 3) / 4;     // fused h+x stage
    const int GEMMB = (NN / 16 * 64 + 255) / 256;

    hipMemsetAsync(dinv, 0, NN * 4, stream);
    hipMemsetAsync(count, 0, NN * 4, stream);

    k_deg_cast_prep<<<EB + CB + 25, 256, 0, stream>>>(
        src, dst, ew, dinv, count, rank, x, h0, x_bf, h0_bf,
        Wx, Wh, bx, bh, BfragZR, BfragHT, biasC);
    k_scan1<<<NB, 256, 0, stream>>>(count, S, bsums);
    k_scan2<<<1, 64, 0, stream>>>(bsums, NB);
    k_scan3_dinv<<<NBLK, 256, 0, stream>>>(S, count, bsums, rowptr, dinv);
    k_place<<<EB, 256, 0, stream>>>(src, dst, ew, rank, dinv, rowptr, csr_ew);

    // stage 1: Th1 = P(h0), Tx1 = P(x)
    k_stage<<<STAGEB, 256, 0, stream>>>(h0_bf, nullptr, 1.f, x_bf, nullptr, 1.f,
                                        rowptr, csr_ew, Th1, Tx1);
    // stage 2: Th2 = 2P(Th1) - h0, Tx2 = 2P(Tx1) - x
    k_stage<<<STAGEB, 256, 0, stream>>>(Th1, h0_bf, 2.f, Tx1, x_bf, 2.f,
                                        rowptr, csr_ew, Th2, Tx2);

    // z and r gates (r fused into hr = r*h0)
    k_mfma_zr<<<GEMMB, 256, 0, stream>>>(x_bf, Tx1, Tx2, h0_bf, Th1, Th2,
                                         BfragZR, biasC, h0, z_bf, hr_bf);
    // propagate hr (reuse Th1/Th2 as Thr1/Thr2)
    k_prop64<<<PROPB, 256, 0, stream>>>(hr_bf, nullptr, 1.f, rowptr, csr_ew, Th1);
    k_prop64<<<PROPB, 256, 0, stream>>>(Th1, hr_bf, 2.f, rowptr, csr_ew, Th2);
    // htilde gate + GRU combine -> h (written directly to d_out)
    k_mfma_ht<<<GEMMB, 256, 0, stream>>>(x_bf, Tx1, Tx2, hr_bf, Th1, Th2,
                                         BfragHT, biasC, z_bf, h0, hout);
    // decoder
    k_ylin<<<(NN * 8 + 255) / 256, 256, 0, stream>>>(hout, Wlin, blin, yout);
}